// Round 1
// baseline (188.216 us; speedup 1.0000x reference)
//
#include <hip/hip_runtime.h>
#include <hip/hip_bf16.h>

typedef __attribute__((ext_vector_type(8))) short bf16x8;
typedef __attribute__((ext_vector_type(4))) float f32x4;

#define DIM    2048
#define GDIM   512
#define BM     128
#define BN     128
#define BK     64
#define NKT    8      // GDIM / BK

__device__ __forceinline__ short f2bf(float f) {
  __bf16 h = (__bf16)f;             // fptrunc -> v_cvt (RNE) on gfx950
  return __builtin_bit_cast(short, h);
}

__global__ __launch_bounds__(256, 2)
void bdlinear_kernel(const float* __restrict__ X, const float* __restrict__ W,
                     const float* __restrict__ Bias, float* __restrict__ O) {
  // MFMA-native fragment layout: [buf][kblock(8)][row(128)][8 bf16] = 16KB/buf/matrix
  __shared__ short lsA[2][8][128][8];
  __shared__ short lsB[2][8][128][8];

  int bid = blockIdx.x;
  // XCD-aware bijective swizzle: 1024 blocks, 8 XCDs, 128 blocks per XCD chunk
  bid = (bid & 7) * 128 + (bid >> 3);
  const int n_tile = bid & 15;   // n fastest: neighbors share W block + L2 A panels
  const int m_tile = bid >> 4;
  const int g      = n_tile >> 2;          // which diagonal block
  const int row0   = m_tile * BM;
  const int col0   = n_tile * BN;
  const long k0g   = (long)g * GDIM;

  const int t    = threadIdx.x;
  const int r    = t & 127;                // row (A) / out-feature (B) this thread stages
  const int kb4  = (t >> 7) * 4;           // kblock base: 0 or 4
  const int kcol0 = kb4 * 8;               // 0 or 32

  const float* pA = X + (size_t)(row0 + r) * DIM + k0g + kcol0;
  const float* pB = W + (size_t)(col0 + r) * DIM + k0g + kcol0;

  const int lane = t & 63;
  const int wid  = t >> 6;
  const int wm   = (wid & 1) * 64;
  const int wn   = (wid >> 1) * 64;
  const int lrow = lane & 15;
  const int lkb  = lane >> 4;

  f32x4 acc[4][4] = {};
  f32x4 va[8], vb[8];

  // ---- prologue: stage tile 0 into buf 0
  #pragma unroll
  for (int j = 0; j < 4; ++j) {
    va[2*j]   = *(const f32x4*)(pA + j*8);
    va[2*j+1] = *(const f32x4*)(pA + j*8 + 4);
    vb[2*j]   = *(const f32x4*)(pB + j*8);
    vb[2*j+1] = *(const f32x4*)(pB + j*8 + 4);
  }
  #pragma unroll
  for (int j = 0; j < 4; ++j) {
    bf16x8 wa, wb;
    #pragma unroll
    for (int e = 0; e < 4; ++e) {
      wa[e]   = f2bf(va[2*j][e]);
      wa[4+e] = f2bf(va[2*j+1][e]);
      wb[e]   = f2bf(vb[2*j][e]);
      wb[4+e] = f2bf(vb[2*j+1][e]);
    }
    *(bf16x8*)&lsA[0][kb4 + j][r][0] = wa;
    *(bf16x8*)&lsB[0][kb4 + j][r][0] = wb;
  }
  __syncthreads();

  for (int kt = 0; kt < NKT; ++kt) {
    const int buf = kt & 1;
    // T14: issue next tile's global loads EARLY (hide HBM under MFMA)
    if (kt + 1 < NKT) {
      const float* qA = pA + (kt + 1) * BK;
      const float* qB = pB + (kt + 1) * BK;
      #pragma unroll
      for (int j = 0; j < 4; ++j) {
        va[2*j]   = *(const f32x4*)(qA + j*8);
        va[2*j+1] = *(const f32x4*)(qA + j*8 + 4);
        vb[2*j]   = *(const f32x4*)(qB + j*8);
        vb[2*j+1] = *(const f32x4*)(qB + j*8 + 4);
      }
    }
    // compute current buffer: 2 k-steps of 32, 4x4 fragments
    #pragma unroll
    for (int ks = 0; ks < 2; ++ks) {
      bf16x8 af[4], bfr[4];
      #pragma unroll
      for (int mi = 0; mi < 4; ++mi)
        af[mi] = *(const bf16x8*)&lsA[buf][ks*4 + lkb][wm + mi*16 + lrow][0];
      #pragma unroll
      for (int ni = 0; ni < 4; ++ni)
        bfr[ni] = *(const bf16x8*)&lsB[buf][ks*4 + lkb][wn + ni*16 + lrow][0];
      #pragma unroll
      for (int mi = 0; mi < 4; ++mi)
        #pragma unroll
        for (int ni = 0; ni < 4; ++ni)
          acc[mi][ni] = __builtin_amdgcn_mfma_f32_16x16x32_bf16(
              af[mi], bfr[ni], acc[mi][ni], 0, 0, 0);
    }
    // write-late: convert + ds_write into the other buffer
    if (kt + 1 < NKT) {
      #pragma unroll
      for (int j = 0; j < 4; ++j) {
        bf16x8 wa, wb;
        #pragma unroll
        for (int e = 0; e < 4; ++e) {
          wa[e]   = f2bf(va[2*j][e]);
          wa[4+e] = f2bf(va[2*j+1][e]);
          wb[e]   = f2bf(vb[2*j][e]);
          wb[4+e] = f2bf(vb[2*j+1][e]);
        }
        *(bf16x8*)&lsA[buf ^ 1][kb4 + j][r][0] = wa;
        *(bf16x8*)&lsB[buf ^ 1][kb4 + j][r][0] = wb;
      }
    }
    __syncthreads();
  }

  // epilogue: bias add + fp32 store. C/D layout: col=lane&15, row=(lane>>4)*4+i
  #pragma unroll
  for (int ni = 0; ni < 4; ++ni) {
    const int ocol = col0 + wn + ni * 16 + lrow;
    const float bias = Bias[ocol];
    #pragma unroll
    for (int mi = 0; mi < 4; ++mi) {
      #pragma unroll
      for (int i = 0; i < 4; ++i) {
        const int orow = row0 + wm + mi * 16 + lkb * 4 + i;
        O[(size_t)orow * DIM + ocol] = acc[mi][ni][i] + bias;
      }
    }
  }
}

extern "C" void kernel_launch(void* const* d_in, const int* in_sizes, int n_in,
                              void* d_out, int out_size, void* d_ws, size_t ws_size,
                              hipStream_t stream) {
  const float* X = (const float*)d_in[0];
  const float* W = (const float*)d_in[1];
  const float* B = (const float*)d_in[2];
  float* O       = (float*)d_out;
  dim3 grid(64 * 16), block(256);
  hipLaunchKernelGGL(bdlinear_kernel, grid, block, 0, stream, X, W, B, O);
}

// Round 2
// 184.514 us; speedup vs baseline: 1.0201x; 1.0201x over previous
//
#include <hip/hip_runtime.h>
#include <hip/hip_bf16.h>

typedef __attribute__((ext_vector_type(8))) short bf16x8;
typedef __attribute__((ext_vector_type(4))) float f32x4;

#define DIM    2048
#define GDIM   512
#define BM     128
#define BN     128
#define BK     64
#define NKT    8      // GDIM / BK

__device__ __forceinline__ short f2bf(float f) {
  __bf16 h = (__bf16)f;
  return __builtin_bit_cast(short, h);
}

__global__ __launch_bounds__(512, 4)
void bdlinear_kernel(const float* __restrict__ X, const float* __restrict__ W,
                     const float* __restrict__ Bias, float* __restrict__ O) {
  // [buf][mat(A/B)][kblock(8)][row(128)][8 bf16]  = 64 KB total
  __shared__ short ls[2][2][8][128][8];

  int bid = blockIdx.x;
  // XCD-aware bijective swizzle: 1024 blocks, 8 XCDs, 128-block chunks
  bid = (bid & 7) * 128 + (bid >> 3);
  const int n_tile = bid & 15;
  const int m_tile = bid >> 4;
  const int g      = n_tile >> 2;          // diagonal block id
  const int row0   = m_tile * BM;
  const int col0   = n_tile * BN;
  const long k0    = (long)g * GDIM;

  const int t   = threadIdx.x;
  // staging job: t<256 -> A (X rows), t>=256 -> B (W rows).
  // h=t&255: sr=h&127 is the row, kh=h>>7 picks 32-float half of the 64-k tile.
  const int isB = t >> 8;
  const int h   = t & 255;
  const int sr  = h & 127;
  const int kh  = h >> 7;
  const float* sp = (isB ? (W + (size_t)(col0 + sr) * DIM)
                         : (X + (size_t)(row0 + sr) * DIM)) + k0 + kh * 32;

  const int lane = t & 63;
  const int wid  = t >> 6;                 // 8 waves: 2M x 4N
  const int wm   = (wid & 1) * 64;
  const int wn   = (wid >> 1) * 32;
  const int lrow = lane & 15;
  const int lkb  = lane >> 4;

  f32x4 acc[4][2] = {};
  f32x4 va[8];

  // ---- prologue: stage tile 0 into buf 0
  #pragma unroll
  for (int j = 0; j < 8; ++j) va[j] = *(const f32x4*)(sp + j * 4);
  #pragma unroll
  for (int j = 0; j < 4; ++j) {
    bf16x8 w;
    #pragma unroll
    for (int e = 0; e < 4; ++e) {
      w[e]     = f2bf(va[2*j][e]);
      w[4 + e] = f2bf(va[2*j + 1][e]);
    }
    *(bf16x8*)&ls[0][isB][kh * 4 + j][sr][0] = w;
  }
  __syncthreads();

  for (int kt = 0; kt < NKT; ++kt) {
    const int p = kt & 1;
    // issue next tile's global loads EARLY (T14: hide HBM under MFMA)
    if (kt + 1 < NKT) {
      const float* q = sp + (kt + 1) * BK;
      #pragma unroll
      for (int j = 0; j < 8; ++j) va[j] = *(const f32x4*)(q + j * 4);
    }
    // compute current buffer: 2 k-steps of 32
    #pragma unroll
    for (int ks = 0; ks < 2; ++ks) {
      bf16x8 af[4], bfr[2];
      #pragma unroll
      for (int mi = 0; mi < 4; ++mi)
        af[mi] = *(const bf16x8*)&ls[p][0][ks * 4 + lkb][wm + mi * 16 + lrow][0];
      #pragma unroll
      for (int ni = 0; ni < 2; ++ni)
        bfr[ni] = *(const bf16x8*)&ls[p][1][ks * 4 + lkb][wn + ni * 16 + lrow][0];
      #pragma unroll
      for (int mi = 0; mi < 4; ++mi)
        #pragma unroll
        for (int ni = 0; ni < 2; ++ni)
          acc[mi][ni] = __builtin_amdgcn_mfma_f32_16x16x32_bf16(
              af[mi], bfr[ni], acc[mi][ni], 0, 0, 0);
    }
    // write-late: convert + ds_write into the other buffer
    if (kt + 1 < NKT) {
      #pragma unroll
      for (int j = 0; j < 4; ++j) {
        bf16x8 w;
        #pragma unroll
        for (int e = 0; e < 4; ++e) {
          w[e]     = f2bf(va[2*j][e]);
          w[4 + e] = f2bf(va[2*j + 1][e]);
        }
        *(bf16x8*)&ls[p ^ 1][isB][kh * 4 + j][sr][0] = w;
      }
    }
    __syncthreads();
  }

  // epilogue: bias + fp32 store. C/D: col=lane&15, row=(lane>>4)*4+i
  #pragma unroll
  for (int ni = 0; ni < 2; ++ni) {
    const int ocol = col0 + wn + ni * 16 + lrow;
    const float bias = Bias[ocol];
    #pragma unroll
    for (int mi = 0; mi < 4; ++mi) {
      #pragma unroll
      for (int i = 0; i < 4; ++i) {
        const int orow = row0 + wm + mi * 16 + lkb * 4 + i;
        O[(size_t)orow * DIM + ocol] = acc[mi][ni][i] + bias;
      }
    }
  }
}

extern "C" void kernel_launch(void* const* d_in, const int* in_sizes, int n_in,
                              void* d_out, int out_size, void* d_ws, size_t ws_size,
                              hipStream_t stream) {
  const float* X = (const float*)d_in[0];
  const float* W = (const float*)d_in[1];
  const float* B = (const float*)d_in[2];
  float* O       = (float*)d_out;
  dim3 grid(64 * 16), block(512);
  hipLaunchKernelGGL(bdlinear_kernel, grid, block, 0, stream, X, W, B, O);
}

// Round 3
// 161.756 us; speedup vs baseline: 1.1636x; 1.1407x over previous
//
#include <hip/hip_runtime.h>
#include <hip/hip_bf16.h>

typedef __attribute__((ext_vector_type(8))) short bf16x8;
typedef __attribute__((ext_vector_type(4))) float f32x4;

#define DIM    2048
#define GDIM   512
#define BM     128
#define BN     128
#define BK     64
#define NKT    8      // GDIM / BK

__device__ __forceinline__ short f2bf(float f) {
  __bf16 h = (__bf16)f;
  return __builtin_bit_cast(short, h);
}

__global__ __launch_bounds__(512, 4)
void bdlinear_kernel(const float* __restrict__ X, const float* __restrict__ W,
                     const float* __restrict__ Bias, float* __restrict__ O) {
  // [buf][mat][row(128)][k(64)] bf16, XOR-swizzled 16B granules. 64 KB total.
  __shared__ short ls[2][2][128][64];

  int bid = blockIdx.x;
  // XCD-aware bijective swizzle: 1024 blocks, 8 XCDs, 128-block chunks
  bid = (bid & 7) * 128 + (bid >> 3);
  const int n_tile = bid & 15;
  const int m_tile = bid >> 4;
  const int g      = n_tile >> 2;          // diagonal block id
  const int row0   = m_tile * BM;
  const int col0   = n_tile * BN;
  const long k0    = (long)g * GDIM;

  const int t  = threadIdx.x;
  // Coalesced staging: chunk c2 = 8 contiguous floats; lane-adjacent chunks
  // are address-adjacent (wave instr covers 8 rows x 256B contiguous).
  const int c2 = t & 7;                    // 32B chunk within 64-float row
  const int r0 = (t >> 3) & 63;           // rows r0 and r0+64
  const float* pA = X + (size_t)(row0 + r0) * DIM + k0 + c2 * 8;
  const float* pB = W + (size_t)(col0 + r0) * DIM + k0 + c2 * 8;
  const int gsw = (c2 ^ (r0 & 7)) * 8;    // swizzled granule (elem offset); same for r0+64

  const int lane = t & 63;
  const int wid  = t >> 6;                 // 8 waves: 2M x 4N
  const int wm   = (wid & 1) * 64;
  const int wn   = (wid >> 1) * 32;
  const int lrow = lane & 15;
  const int lkb  = lane >> 4;
  const int lsw  = lrow & 7;               // read-side swizzle key

  f32x4 acc[4][2] = {};
  f32x4 va[8];

  auto loadTile = [&](int kt) {
    const float* qA = pA + kt * BK;
    const float* qB = pB + kt * BK;
    va[0] = *(const f32x4*)(qA);
    va[1] = *(const f32x4*)(qA + 4);
    va[2] = *(const f32x4*)(qA + 64 * DIM);
    va[3] = *(const f32x4*)(qA + 64 * DIM + 4);
    va[4] = *(const f32x4*)(qB);
    va[5] = *(const f32x4*)(qB + 4);
    va[6] = *(const f32x4*)(qB + 64 * DIM);
    va[7] = *(const f32x4*)(qB + 64 * DIM + 4);
  };
  auto cvtWrite = [&](int buf) {
    #pragma unroll
    for (int j = 0; j < 4; ++j) {
      bf16x8 w;
      #pragma unroll
      for (int e = 0; e < 4; ++e) {
        w[e]     = f2bf(va[2 * j][e]);
        w[4 + e] = f2bf(va[2 * j + 1][e]);
      }
      const int mat = j >> 1;              // 0: A rows, 1: B rows
      const int rr  = r0 + (j & 1) * 64;
      *(bf16x8*)&ls[buf][mat][rr][gsw] = w;
    }
  };

  // ---- prologue: stage tile 0 into buf 0
  loadTile(0);
  cvtWrite(0);
  __syncthreads();

  for (int kt = 0; kt < NKT; ++kt) {
    const int p = kt & 1;
    // issue next tile's global loads EARLY; fence so they can't sink
    if (kt + 1 < NKT) {
      loadTile(kt + 1);
      __builtin_amdgcn_sched_barrier(0);
    }
    // compute current buffer: 2 k-steps of 32
    #pragma unroll
    for (int ks = 0; ks < 2; ++ks) {
      const int ge = ((ks * 4 + lkb) ^ lsw) * 8;   // swizzled granule elem-offset
      bf16x8 af[4], bfr[2];
      #pragma unroll
      for (int mi = 0; mi < 4; ++mi)
        af[mi] = *(const bf16x8*)&ls[p][0][wm + mi * 16 + lrow][ge];
      #pragma unroll
      for (int ni = 0; ni < 2; ++ni)
        bfr[ni] = *(const bf16x8*)&ls[p][1][wn + ni * 16 + lrow][ge];
      #pragma unroll
      for (int mi = 0; mi < 4; ++mi)
        #pragma unroll
        for (int ni = 0; ni < 2; ++ni)
          acc[mi][ni] = __builtin_amdgcn_mfma_f32_16x16x32_bf16(
              af[mi], bfr[ni], acc[mi][ni], 0, 0, 0);
    }
    // write-late: convert + ds_write into the other buffer
    if (kt + 1 < NKT) {
      __builtin_amdgcn_sched_barrier(0);
      cvtWrite(p ^ 1);
    }
    __syncthreads();
  }

  // epilogue: bias + fp32 store. C/D: col=lane&15, row=(lane>>4)*4+i
  #pragma unroll
  for (int ni = 0; ni < 2; ++ni) {
    const int ocol = col0 + wn + ni * 16 + lrow;
    const float bias = Bias[ocol];
    #pragma unroll
    for (int mi = 0; mi < 4; ++mi) {
      #pragma unroll
      for (int i = 0; i < 4; ++i) {
        const int orow = row0 + wm + mi * 16 + lkb * 4 + i;
        O[(size_t)orow * DIM + ocol] = acc[mi][ni][i] + bias;
      }
    }
  }
}

extern "C" void kernel_launch(void* const* d_in, const int* in_sizes, int n_in,
                              void* d_out, int out_size, void* d_ws, size_t ws_size,
                              hipStream_t stream) {
  const float* X = (const float*)d_in[0];
  const float* W = (const float*)d_in[1];
  const float* B = (const float*)d_in[2];
  float* O       = (float*)d_out;
  dim3 grid(64 * 16), block(512);
  hipLaunchKernelGGL(bdlinear_kernel, grid, block, 0, stream, X, W, B, O);
}

// Round 5
// 159.202 us; speedup vs baseline: 1.1822x; 1.0160x over previous
//
#include <hip/hip_runtime.h>
#include <hip/hip_bf16.h>

typedef __attribute__((ext_vector_type(8))) short bf16x8;
typedef __attribute__((ext_vector_type(4))) float f32x4;

#define DIM  2048
#define GDIM 512
#define BM   128
#define BN   128
#define BK   32
#define NKT  16     // GDIM / BK

__device__ __forceinline__ short f2bf(float f) {
  __bf16 h = (__bf16)f;
  return __builtin_bit_cast(short, h);
}

__device__ __forceinline__ void gload_lds16(const float* g, float* l) {
  __builtin_amdgcn_global_load_lds(
      (const __attribute__((address_space(1))) void*)g,
      (__attribute__((address_space(3))) void*)l, 16, 0, 0);
}

__global__ __launch_bounds__(512, 4)
void bdlinear_kernel(const float* __restrict__ X, const float* __restrict__ W,
                     const float* __restrict__ Bias, float* __restrict__ O) {
  // [buf][ A: 128 rows x 32 f32 | B: 128 rows x 32 f32 ]  = 64 KB total.
  // Row = 8 x 16B granules; content XOR-swizzled: LDS[row][g] = glob[row][g ^ (row&7)]
  __shared__ float ls[2][8192];

  int bid = blockIdx.x;
  // XCD-aware bijective swizzle: each XCD owns 8 m_tiles x all n_tiles
  bid = (bid & 7) * 128 + (bid >> 3);
  const int n_tile = bid & 15;
  const int m_tile = bid >> 4;
  const int g      = n_tile >> 2;          // diagonal block id
  const int row0   = m_tile * BM;
  const int col0   = n_tile * BN;
  const long k0    = (long)g * GDIM;

  const int t    = threadIdx.x;
  const int lane = t & 63;
  const int wid  = t >> 6;                 // 8 waves

  // --- staging: 32 wave-instructions of 1KB each (16 A + 16 B), 4 per wave.
  // lane -> (r = lane>>3 row within 8-row span, gl = lane&7 granule), source
  // granule pre-swizzled so linear LDS dest holds swizzled content.
  const int r    = lane >> 3;
  const int srcg = (lane & 7) ^ r;
  const float* gsrc[4];
  int ldoff[4];                            // float offset within a buffer
  #pragma unroll
  for (int j = 0; j < 4; ++j) {
    const int seg = wid * 4 + j;           // 0..31
    ldoff[j] = seg * 256;                  // 1KB per segment
    if (seg < 16) {                        // A: X rows
      const int arow = seg * 8 + r;
      gsrc[j] = X + (size_t)(row0 + arow) * DIM + k0 + srcg * 4;
    } else {                               // B: W rows (out features)
      const int brow = (seg - 16) * 8 + r;
      gsrc[j] = W + (size_t)(col0 + brow) * DIM + k0 + srcg * 4;
    }
  }

  // --- compute mapping: 8 waves = 2M x 4N, each wave 64x32 out
  const int wm   = (wid & 1) * 64;
  const int wn   = (wid >> 1) * 32;
  const int lrow = lane & 15;
  const int lkb  = lane >> 4;              // k-granule pair base = 2*lkb

  f32x4 acc[4][2] = {};

  auto STAGE = [&](int buf, int kt) {
    #pragma unroll
    for (int j = 0; j < 4; ++j)
      gload_lds16(gsrc[j] + kt * BK, &ls[buf][ldoff[j]]);
  };

  // prologue
  STAGE(0, 0);
  __syncthreads();                          // drains vmcnt(0)

  for (int kt = 0; kt < NKT; ++kt) {
    const int p = kt & 1;
    if (kt + 1 < NKT) STAGE(p ^ 1, kt + 1); // async, direct-to-LDS, can't sink

    // fragments: read swizzled fp32, convert to bf16
    bf16x8 af[4], bfr[2];
    #pragma unroll
    for (int mi = 0; mi < 4; ++mi) {
      const int row = wm + mi * 16 + lrow;
      const int s   = row & 7;
      const f32x4 a0 = *(const f32x4*)&ls[p][row * 32 + (((lkb * 2)     ^ s) * 4)];
      const f32x4 a1 = *(const f32x4*)&ls[p][row * 32 + (((lkb * 2 + 1) ^ s) * 4)];
      #pragma unroll
      for (int e = 0; e < 4; ++e) { af[mi][e] = f2bf(a0[e]); af[mi][4 + e] = f2bf(a1[e]); }
    }
    #pragma unroll
    for (int ni = 0; ni < 2; ++ni) {
      const int row = wn + ni * 16 + lrow;
      const int s   = row & 7;
      const f32x4 b0 = *(const f32x4*)&ls[p][4096 + row * 32 + (((lkb * 2)     ^ s) * 4)];
      const f32x4 b1 = *(const f32x4*)&ls[p][4096 + row * 32 + (((lkb * 2 + 1) ^ s) * 4)];
      #pragma unroll
      for (int e = 0; e < 4; ++e) { bfr[ni][e] = f2bf(b0[e]); bfr[ni][4 + e] = f2bf(b1[e]); }
    }
    #pragma unroll
    for (int mi = 0; mi < 4; ++mi)
      #pragma unroll
      for (int ni = 0; ni < 2; ++ni)
        acc[mi][ni] = __builtin_amdgcn_mfma_f32_16x16x32_bf16(
            af[mi], bfr[ni], acc[mi][ni], 0, 0, 0);

    __syncthreads();  // implicit vmcnt(0): next tile landed; buffers safe to swap
  }

  // epilogue: bias + fp32 store. C/D: col=lane&15, row=(lane>>4)*4+i
  #pragma unroll
  for (int ni = 0; ni < 2; ++ni) {
    const int ocol = col0 + wn + ni * 16 + lrow;
    const float bias = Bias[ocol];
    #pragma unroll
    for (int mi = 0; mi < 4; ++mi) {
      #pragma unroll
      for (int i = 0; i < 4; ++i) {
        const int orow = row0 + wm + mi * 16 + lkb * 4 + i;
        O[(size_t)orow * DIM + ocol] = acc[mi][ni][i] + bias;
      }
    }
  }
}

extern "C" void kernel_launch(void* const* d_in, const int* in_sizes, int n_in,
                              void* d_out, int out_size, void* d_ws, size_t ws_size,
                              hipStream_t stream) {
  const float* X = (const float*)d_in[0];
  const float* W = (const float*)d_in[1];
  const float* B = (const float*)d_in[2];
  float* O       = (float*)d_out;
  dim3 grid(64 * 16), block(512);
  hipLaunchKernelGGL(bdlinear_kernel, grid, block, 0, stream, X, W, B, O);
}

// Round 6
// 145.400 us; speedup vs baseline: 1.2945x; 1.0949x over previous
//
#include <hip/hip_runtime.h>
#include <hip/hip_bf16.h>

typedef __attribute__((ext_vector_type(8))) short bf16x8;
typedef __attribute__((ext_vector_type(4))) float f32x4;

#define DIM   2048
#define GDIM  512
#define NXCH  2097152   // 8192*2048/8 X chunks
#define NWCH  131072    // 2048*512/8 W-diag chunks
#define NTOT  (NXCH + NWCH)

__device__ __forceinline__ short f2bf(float f) {
  __bf16 h = (__bf16)f;
  return __builtin_bit_cast(short, h);
}

__device__ __forceinline__ void gload_lds16(const short* g, short* l) {
  __builtin_amdgcn_global_load_lds(
      (const __attribute__((address_space(1))) void*)g,
      (__attribute__((address_space(3))) void*)l, 16, 0, 0);
}

// ---------------- kernel 1: fp32 -> bf16 convert (X full, W diag blocks) ---
__global__ __launch_bounds__(256)
void cvt_kernel(const float* __restrict__ X, const float* __restrict__ W,
                short* __restrict__ Xbf, short* __restrict__ Wbf) {
  const int stride = gridDim.x * blockDim.x;
  for (int idx = blockIdx.x * blockDim.x + threadIdx.x; idx < NTOT; idx += stride) {
    const float* src;
    short* dst;
    if (idx < NXCH) {                       // X: flat contiguous convert
      src = X + (size_t)idx * 8;
      dst = Xbf + (size_t)idx * 8;
    } else {                                // W: pack diag block of row j
      const int e = (idx - NXCH) * 8;       // e = j*512 + k
      const int j = e >> 9;
      const int k = e & 511;
      src = W + (size_t)j * DIM + ((j >> 9) << 9) + k;
      dst = Wbf + e;
    }
    const f32x4 a = ((const f32x4*)src)[0];
    const f32x4 b = ((const f32x4*)src)[1];
    bf16x8 o;
    #pragma unroll
    for (int e2 = 0; e2 < 4; ++e2) { o[e2] = f2bf(a[e2]); o[4 + e2] = f2bf(b[e2]); }
    *(bf16x8*)dst = o;
  }
}

// ---------------- kernel 2: bf16 block-diag GEMM (m97 structure) ----------
__global__ __launch_bounds__(256, 2)
void gemm_kernel(const short* __restrict__ Xbf, const short* __restrict__ Wbf,
                 const float* __restrict__ Bias, float* __restrict__ O) {
  // [buf][mat][row(128)][k(64)] bf16 = 64KB. Content XOR-swizzled per 16B
  // granule: ls[row][g] = glob[row][g ^ (row&7)] (via pre-swizzled source).
  __shared__ short ls[2][2][128][64];

  int bid = blockIdx.x;
  bid = (bid & 7) * 128 + (bid >> 3);       // XCD-aware bijective swizzle
  const int n_tile = bid & 15;
  const int m_tile = bid >> 4;
  const int g      = n_tile >> 2;
  const int row0   = m_tile * 128;
  const int col0   = n_tile * 128;

  const int t    = threadIdx.x;
  const int lane = t & 63;
  const int wid  = t >> 6;                  // 4 waves, 2M x 2N, 64x64 each

  // staging: 16 A segs + 16 B segs of 1KB (8 rows x 64 bf16); 4+4 per wave
  const int r    = lane >> 3;               // row within 8-row seg
  const int srcg = (lane & 7) ^ r;          // pre-swizzled 16B granule
  const short* gA[4];
  const short* gB[4];
  short* dA[4];
  short* dB[4];
  #pragma unroll
  for (int j = 0; j < 4; ++j) {
    const int s = wid * 4 + j;              // seg 0..15
    gA[j] = Xbf + (size_t)(row0 + s * 8 + r) * DIM + g * GDIM + srcg * 8;
    gB[j] = Wbf + (size_t)(col0 + s * 8 + r) * GDIM + srcg * 8;
    dA[j] = &ls[0][0][s * 8][0];            // +lane*16B applied by HW
    dB[j] = &ls[0][1][s * 8][0];
  }

  const int wm   = (wid & 1) * 64;
  const int wn   = (wid >> 1) * 64;
  const int lrow = lane & 15;
  const int lkb  = lane >> 4;

  f32x4 acc[4][4] = {};

  auto STAGE = [&](int buf, int kt) {
    const int bo = buf * (2 * 128 * 64);    // shorts per buffer
    #pragma unroll
    for (int j = 0; j < 4; ++j) {
      gload_lds16(gA[j] + kt * 64, dA[j] + bo);
      gload_lds16(gB[j] + kt * 64, dB[j] + bo);
    }
  };

  STAGE(0, 0);
  __syncthreads();

  for (int kt = 0; kt < 8; ++kt) {
    const int p = kt & 1;
    if (kt + 1 < 8) STAGE(p ^ 1, kt + 1);

    #pragma unroll
    for (int ks = 0; ks < 2; ++ks) {
      bf16x8 af[4], bfr[4];
      #pragma unroll
      for (int mi = 0; mi < 4; ++mi) {
        const int row = wm + mi * 16 + lrow;
        af[mi] = *(const bf16x8*)&ls[p][0][row][(((ks * 4 + lkb) ^ (row & 7)) * 8)];
      }
      #pragma unroll
      for (int ni = 0; ni < 4; ++ni) {
        const int row = wn + ni * 16 + lrow;
        bfr[ni] = *(const bf16x8*)&ls[p][1][row][(((ks * 4 + lkb) ^ (row & 7)) * 8)];
      }
      #pragma unroll
      for (int mi = 0; mi < 4; ++mi)
        #pragma unroll
        for (int ni = 0; ni < 4; ++ni)
          acc[mi][ni] = __builtin_amdgcn_mfma_f32_16x16x32_bf16(
              af[mi], bfr[ni], acc[mi][ni], 0, 0, 0);
    }
    __syncthreads();
  }

  // epilogue: bias + fp32 store. C/D: col=lane&15, row=(lane>>4)*4+i
  #pragma unroll
  for (int ni = 0; ni < 4; ++ni) {
    const int ocol = col0 + wn + ni * 16 + lrow;
    const float bias = Bias[ocol];
    #pragma unroll
    for (int mi = 0; mi < 4; ++mi) {
      #pragma unroll
      for (int i = 0; i < 4; ++i) {
        const int orow = row0 + wm + mi * 16 + lkb * 4 + i;
        O[(size_t)orow * DIM + ocol] = acc[mi][ni][i] + bias;
      }
    }
  }
}

extern "C" void kernel_launch(void* const* d_in, const int* in_sizes, int n_in,
                              void* d_out, int out_size, void* d_ws, size_t ws_size,
                              hipStream_t stream) {
  const float* X = (const float*)d_in[0];
  const float* W = (const float*)d_in[1];
  const float* B = (const float*)d_in[2];
  float* O       = (float*)d_out;
  short* Xbf     = (short*)d_ws;                       // 32 MB
  short* Wbf     = Xbf + (size_t)8192 * 2048;          // +2 MB packed diag

  hipLaunchKernelGGL(cvt_kernel, dim3(2048), dim3(256), 0, stream, X, W, Xbf, Wbf);
  hipLaunchKernelGGL(gemm_kernel, dim3(1024), dim3(256), 0, stream, Xbf, Wbf, B, O);
}